// Round 3
// baseline (470.598 us; speedup 1.0000x reference)
//
#include <hip/hip_runtime.h>
#include <hip/hip_bf16.h>

typedef __attribute__((ext_vector_type(8))) short short8;
typedef __attribute__((ext_vector_type(4))) float floatx4;

#define B_ 8
#define T_ 1024
#define S_ 1500
#define SP 1536
#define D_ 1024
#define H_ 16
#define DH 64
// q-scale with log2(e) folded in: exp(x) = exp2(x * log2e)
#define SCALE2_ 0.1803368801111244f

__device__ __forceinline__ unsigned short f2bf(float f) {
  unsigned u = __float_as_uint(f);
  u += 0x7fffu + ((u >> 16) & 1u);
  return (unsigned short)(u >> 16);
}

__device__ __forceinline__ floatx4 mfma16(short8 a, short8 b, floatx4 c) {
  return __builtin_amdgcn_mfma_f32_16x16x32_bf16(a, b, c, 0, 0, 0);
}

// ---------------- prep: fused fp32 -> bf16 cast for x, wq, wo ----------------
#define N1C (B_ * T_ * D_ / 4)
#define N2C (D_ * D_ / 4)
__global__ void cast3_kernel(const float* __restrict__ x, const float* __restrict__ wq,
                             const float* __restrict__ wo, unsigned short* __restrict__ xb,
                             unsigned short* __restrict__ wqb,
                             unsigned short* __restrict__ wob) {
  int i = blockIdx.x * blockDim.x + threadIdx.x;
  const float* src;
  unsigned short* dst;
  int j;
  if (i < N1C) {
    src = x; dst = xb; j = i;
  } else if (i < N1C + N2C) {
    src = wq; dst = wqb; j = i - N1C;
  } else {
    src = wo; dst = wob; j = i - N1C - N2C;
  }
  float4 v = ((const float4*)src)[j];
  ushort4 o;
  o.x = f2bf(v.x); o.y = f2bf(v.y); o.z = f2bf(v.z); o.w = f2bf(v.w);
  ((ushort4*)dst)[j] = o;
}

// ---------------- prep: K [B,S,H,DH] f32 -> [B,H,SP,DH] bf16, ROW-PERMUTED ------
// staged position p (within each 32-block) holds actual s-offset q*8+half*4+r
// where q=(p>>2)&3, half=(p>>4)&1, r=p&3. Zero-pad actual s >= S_.
__global__ void pack_k_kernel(const float* __restrict__ k,
                              unsigned short* __restrict__ kb) {
  int i = blockIdx.x * blockDim.x + threadIdx.x;  // group of 4 dh
  int dh4 = (i & 15) * 4;
  int j = i >> 4;
  int s = j % SP;   // staged position
  int bh = j / SP;
  if (bh >= B_ * H_) return;
  int b = bh >> 4, h = bh & 15;
  int p = s & 31;
  int src = (s & ~31) + ((p >> 2) & 3) * 8 + ((p >> 4) & 1) * 4 + (p & 3);
  ushort4 o;
  if (src < S_) {
    float4 v = *(const float4*)(k + (((size_t)(b * S_ + src) * H_ + h) * DH) + dh4);
    o.x = f2bf(v.x); o.y = f2bf(v.y); o.z = f2bf(v.z); o.w = f2bf(v.w);
  } else {
    o = make_ushort4(0, 0, 0, 0);
  }
  *(ushort4*)(kb + ((size_t)bh * SP + s) * DH + dh4) = o;
}

// ---------------- prep: V [B,S,H,DH] f32 -> transposed [B,H,DH,SP] bf16 (plain) -
__global__ void pack_vt_kernel(const float* __restrict__ v,
                               unsigned short* __restrict__ vt) {
  __shared__ unsigned short tile[64][72];  // [dh][s], padded
  int st = blockIdx.x, bh = blockIdx.y;
  int b = bh >> 4, h = bh & 15;
  int s0 = st * 64;
  int t = threadIdx.x;
  for (int i = t; i < 1024; i += 256) {
    int sl = i >> 4, dh4 = (i & 15) * 4;
    float4 val = make_float4(0.f, 0.f, 0.f, 0.f);
    if (s0 + sl < S_)
      val = *(const float4*)(v + ((size_t)((b * S_ + s0 + sl) * H_ + h)) * DH + dh4);
    tile[dh4 + 0][sl] = f2bf(val.x);
    tile[dh4 + 1][sl] = f2bf(val.y);
    tile[dh4 + 2][sl] = f2bf(val.z);
    tile[dh4 + 3][sl] = f2bf(val.w);
  }
  __syncthreads();
  for (int i = t; i < 1024; i += 256) {
    int d = i >> 4, s4 = (i & 15) * 4;
    ushort4 o;
    o.x = tile[d][s4]; o.y = tile[d][s4 + 1]; o.z = tile[d][s4 + 2]; o.w = tile[d][s4 + 3];
    *(ushort4*)(vt + ((size_t)bh * DH + d) * SP + s0 + s4) = o;
  }
}

// ---------------- bf16 GEMM  C[m,n] = sum_k A[m,k]*B[n,k]  (+bias epilogues) -----
// epi=0: qs output bf16, (val+bias)*SCALE2 (log2e folded), permuted to [B,H,T,DH]
// epi=1: fp32 output, val+bias, row-major [M,1024]
#define BK 32
#define ASTR 40
__global__ __launch_bounds__(256) void gemm_bt(const unsigned short* __restrict__ A,
                                               const unsigned short* __restrict__ Bm,
                                               const float* __restrict__ bias,
                                               void* __restrict__ outp, int epi) {
  __shared__ unsigned short As[128 * ASTR];
  __shared__ unsigned short Bs[128 * ASTR];
  const int K = 1024;
  int t = threadIdx.x;
  int m0 = blockIdx.y * 128, n0 = blockIdx.x * 128;
  int w = t >> 6, lane = t & 63, quad = lane >> 4, l16 = lane & 15;
  int mw = (w & 1) * 64, nw = (w >> 1) * 64;
  int lrow = t >> 2, lcol = (t & 3) * 8;

  const unsigned short* Ag = A + (size_t)(m0 + lrow) * K + lcol;
  const unsigned short* Bg = Bm + (size_t)(n0 + lrow) * K + lcol;

  floatx4 acc[4][4];
#pragma unroll
  for (int i = 0; i < 4; i++)
#pragma unroll
    for (int j = 0; j < 4; j++) {
      floatx4 z = {0.f, 0.f, 0.f, 0.f};
      acc[i][j] = z;
    }

  int4 a0 = *(const int4*)(Ag);
  int4 a1 = *(const int4*)(Ag + (size_t)64 * K);
  int4 b0 = *(const int4*)(Bg);
  int4 b1 = *(const int4*)(Bg + (size_t)64 * K);

  for (int kt = 0; kt < K / BK; kt++) {
    __syncthreads();
    *(int4*)&As[lrow * ASTR + lcol] = a0;
    *(int4*)&As[(lrow + 64) * ASTR + lcol] = a1;
    *(int4*)&Bs[lrow * ASTR + lcol] = b0;
    *(int4*)&Bs[(lrow + 64) * ASTR + lcol] = b1;
    __syncthreads();
    if (kt + 1 < K / BK) {
      a0 = *(const int4*)(Ag + (kt + 1) * BK);
      a1 = *(const int4*)(Ag + (size_t)64 * K + (kt + 1) * BK);
      b0 = *(const int4*)(Bg + (kt + 1) * BK);
      b1 = *(const int4*)(Bg + (size_t)64 * K + (kt + 1) * BK);
    }
    short8 af[4], bf[4];
#pragma unroll
    for (int mi = 0; mi < 4; mi++)
      af[mi] = *(const short8*)&As[(mw + mi * 16 + l16) * ASTR + quad * 8];
#pragma unroll
    for (int ni = 0; ni < 4; ni++)
      bf[ni] = *(const short8*)&Bs[(nw + ni * 16 + l16) * ASTR + quad * 8];
#pragma unroll
    for (int mi = 0; mi < 4; mi++)
#pragma unroll
      for (int ni = 0; ni < 4; ni++)
        acc[mi][ni] = mfma16(af[mi], bf[ni], acc[mi][ni]);
  }

#pragma unroll
  for (int mi = 0; mi < 4; mi++)
#pragma unroll
    for (int ni = 0; ni < 4; ni++) {
      int row = m0 + mw + mi * 16 + quad * 4;
      int col = n0 + nw + ni * 16 + l16;
      float bcol = bias[col];
#pragma unroll
      for (int r = 0; r < 4; r++) {
        float val = acc[mi][ni][r] + bcol;
        int rr = row + r;
        if (epi == 0) {
          int b = rr >> 10, tt = rr & 1023, h = col >> 6, dh = col & 63;
          ((unsigned short*)outp)[(((size_t)(b * 16 + h) * 1024) + tt) * 64 + dh] =
              f2bf(val * SCALE2_);
        } else {
          ((float*)outp)[(size_t)rr * 1024 + col] = val;
        }
      }
    }
}

// ---------------- fused flash attention, Sc^T scheme, 8-wave blocks ----------
// grid (T/128, B*H), block 512 (8 waves); wave owns 16 t-columns.
// Scores computed transposed: C col = t (lane), row = staged s (quad*4+reg).
// K staged row-permuted so P fragments re-pack in-lane as PV B-operand.
// Softmax in base-2 domain (log2e folded into q scale).
__global__ __launch_bounds__(512, 8) void attn_kernel(
    const unsigned short* __restrict__ qs, const unsigned short* __restrict__ kb,
    const unsigned short* __restrict__ vt, unsigned short* __restrict__ ob) {
  __shared__ unsigned short Ks[128 * 72];   // [staged s][dh] padded
  __shared__ unsigned short Vs[64 * 136];   // [dh][s] padded (plain order)
  int ttile = blockIdx.x, bh = blockIdx.y;
  int b = bh >> 4, h = bh & 15;
  int t = threadIdx.x, w = t >> 6, lane = t & 63, quad = lane >> 4, l16 = lane & 15;

  // Q as B-operand: n = t = l16, k(dh) = quad*8 + j
  const unsigned short* qp =
      qs + ((size_t)bh * T_ + ttile * 128 + w * 16 + l16) * DH + quad * 8;
  short8 qa0 = *(const short8*)(qp);
  short8 qa1 = *(const short8*)(qp + 32);

  const unsigned short* kbase = kb + (size_t)bh * SP * DH;
  const unsigned short* vbase = vt + (size_t)bh * DH * SP;

  floatx4 o[4];  // O^T acc: col=t(l16), row = db*16 + quad*4 + r (= dh)
#pragma unroll
  for (int i = 0; i < 4; i++) {
    floatx4 z = {0.f, 0.f, 0.f, 0.f};
    o[i] = z;
  }
  float mrow = -1e30f, lrow = 0.f;  // per-lane: this lane's t-row state (base-2)

  for (int s0 = 0; s0 < SP; s0 += 128) {
    __syncthreads();
    {
      const int4* src = (const int4*)(kbase + (size_t)s0 * DH);
#pragma unroll
      for (int i = t; i < 128 * DH / 8; i += 512) {
        int row = i >> 3, c = i & 7;
        *(int4*)&Ks[row * 72 + c * 8] = src[i];
      }
#pragma unroll
      for (int i = t; i < 64 * 128 / 8; i += 512) {
        int d = i >> 4, c = i & 15;
        *(int4*)&Vs[d * 136 + c * 8] = *(const int4*)(vbase + (size_t)d * SP + s0 + c * 8);
      }
    }
    __syncthreads();

    // Sc^T: per lane 32 staged-s values of its own t-row
    floatx4 sc[8];
#pragma unroll
    for (int nb = 0; nb < 8; nb++) {
      short8 k0 = *(const short8*)&Ks[(nb * 16 + l16) * 72 + quad * 8];
      short8 k1 = *(const short8*)&Ks[(nb * 16 + l16) * 72 + 32 + quad * 8];
      floatx4 a = {0.f, 0.f, 0.f, 0.f};
      a = mfma16(k0, qa0, a);
      a = mfma16(k1, qa1, a);
      sc[nb] = a;
    }
    if (s0 + 128 > S_) {  // mask padded actual-s (last tile only)
#pragma unroll
      for (int nb = 0; nb < 8; nb++)
#pragma unroll
        for (int r = 0; r < 4; r++) {
          int s_act = s0 + (nb >> 1) * 32 + quad * 8 + (nb & 1) * 4 + r;
          if (s_act >= S_) sc[nb][r] = -1e30f;
        }
    }

    // online softmax (base 2): in-lane over 32 + 2 shfl across quads
    float mx = -1e30f;
#pragma unroll
    for (int nb = 0; nb < 8; nb++) {
      float a0m = fmaxf(sc[nb][0], sc[nb][1]);
      float a1m = fmaxf(sc[nb][2], sc[nb][3]);
      mx = fmaxf(mx, fmaxf(a0m, a1m));
    }
    mx = fmaxf(mx, __shfl_xor(mx, 16));
    mx = fmaxf(mx, __shfl_xor(mx, 32));
    float mnew = fmaxf(mrow, mx);
    float alpha = exp2f(mrow - mnew);
    mrow = mnew;
    float rs = 0.f;
#pragma unroll
    for (int nb = 0; nb < 8; nb++) {
#pragma unroll
      for (int r = 0; r < 4; r++) {
        float p = exp2f(sc[nb][r] - mnew);
        sc[nb][r] = p;
        rs += p;
      }
    }
    rs += __shfl_xor(rs, 16);
    rs += __shfl_xor(rs, 32);
    lrow = lrow * alpha + rs;
#pragma unroll
    for (int db = 0; db < 4; db++) {
      o[db][0] *= alpha; o[db][1] *= alpha; o[db][2] *= alpha; o[db][3] *= alpha;
    }

    // PV: O^T[d][t] += V^T(A) * P(B).  chunk c covers staged s = c*32..c*32+31
#pragma unroll
    for (int c = 0; c < 4; c++) {
      union { short8 v; __hip_bfloat162 h[4]; } pk;
      pk.h[0] = __float22bfloat162_rn(make_float2(sc[2 * c][0], sc[2 * c][1]));
      pk.h[1] = __float22bfloat162_rn(make_float2(sc[2 * c][2], sc[2 * c][3]));
      pk.h[2] = __float22bfloat162_rn(make_float2(sc[2 * c + 1][0], sc[2 * c + 1][1]));
      pk.h[3] = __float22bfloat162_rn(make_float2(sc[2 * c + 1][2], sc[2 * c + 1][3]));
#pragma unroll
      for (int db = 0; db < 4; db++) {
        short8 vf = *(const short8*)&Vs[(db * 16 + l16) * 136 + c * 32 + quad * 8];
        o[db] = mfma16(vf, pk.v, o[db]);
      }
    }
  }

  float inv = 1.0f / lrow;
  int tg = ttile * 128 + w * 16 + l16;
#pragma unroll
  for (int db = 0; db < 4; db++) {
    int dh = db * 16 + quad * 4;
    union { ushort4 s4; __hip_bfloat162 h[2]; } st;
    st.h[0] = __float22bfloat162_rn(make_float2(o[db][0] * inv, o[db][1] * inv));
    st.h[1] = __float22bfloat162_rn(make_float2(o[db][2] * inv, o[db][3] * inv));
    *(ushort4*)(ob + ((size_t)(b * T_ + tg) * H_ + h) * DH + dh) = st.s4;
  }
}

extern "C" void kernel_launch(void* const* d_in, const int* in_sizes, int n_in,
                              void* d_out, int out_size, void* d_ws, size_t ws_size,
                              hipStream_t stream) {
  const float* x  = (const float*)d_in[0];
  const float* k  = (const float*)d_in[1];
  const float* v  = (const float*)d_in[2];
  const float* wq = (const float*)d_in[3];
  const float* bq = (const float*)d_in[4];
  const float* wo = (const float*)d_in[5];
  const float* bo = (const float*)d_in[6];
  float* out = (float*)d_out;

  char* ws = (char*)d_ws;
  unsigned short* xb  = (unsigned short*)(ws + 0);
  unsigned short* wqb = (unsigned short*)(ws + 16777216);
  unsigned short* wob = (unsigned short*)(ws + 18874368);
  unsigned short* kbp = (unsigned short*)(ws + 20971520);
  unsigned short* vtp = (unsigned short*)(ws + 46137344);
  unsigned short* qsp = (unsigned short*)(ws + 71303168);
  unsigned short* obp = (unsigned short*)(ws + 88080384);

  {
    int blocks = (N1C + 2 * N2C) / 256;
    cast3_kernel<<<blocks, 256, 0, stream>>>(x, wq, wo, xb, wqb, wob);
  }
  {
    int groups = B_ * H_ * SP * 16;
    pack_k_kernel<<<groups / 256, 256, 0, stream>>>(k, kbp);
    pack_vt_kernel<<<dim3(SP / 64, B_ * H_), 256, 0, stream>>>(v, vtp);
  }
  gemm_bt<<<dim3(D_ / 128, B_ * T_ / 128), 256, 0, stream>>>(xb, wqb, bq, qsp, 0);
  attn_kernel<<<dim3(T_ / 128, B_ * H_), 512, 0, stream>>>(qsp, kbp, vtp, obp);
  gemm_bt<<<dim3(D_ / 128, B_ * T_ / 128), 256, 0, stream>>>(obp, wob, bo, out, 1);
}

// Round 4
// 403.749 us; speedup vs baseline: 1.1656x; 1.1656x over previous
//
#include <hip/hip_runtime.h>
#include <hip/hip_bf16.h>

typedef __attribute__((ext_vector_type(8))) short short8;
typedef __attribute__((ext_vector_type(4))) float floatx4;

#define B_ 8
#define T_ 1024
#define S_ 1500
#define SP 1536
#define D_ 1024
#define H_ 16
#define DH 64
// q-scale with log2(e) folded in: exp(x) = exp2(x * log2e)
#define SCALE2_ 0.1803368801111244f

__device__ __forceinline__ unsigned short f2bf(float f) {
  unsigned u = __float_as_uint(f);
  u += 0x7fffu + ((u >> 16) & 1u);
  return (unsigned short)(u >> 16);
}

__device__ __forceinline__ floatx4 mfma16(short8 a, short8 b, floatx4 c) {
  return __builtin_amdgcn_mfma_f32_16x16x32_bf16(a, b, c, 0, 0, 0);
}

// ---------------- prep: fused fp32 -> bf16 cast for x, wq, wo ----------------
#define N1C (B_ * T_ * D_ / 4)
#define N2C (D_ * D_ / 4)
__global__ void cast3_kernel(const float* __restrict__ x, const float* __restrict__ wq,
                             const float* __restrict__ wo, unsigned short* __restrict__ xb,
                             unsigned short* __restrict__ wqb,
                             unsigned short* __restrict__ wob) {
  int i = blockIdx.x * blockDim.x + threadIdx.x;
  const float* src;
  unsigned short* dst;
  int j;
  if (i < N1C) {
    src = x; dst = xb; j = i;
  } else if (i < N1C + N2C) {
    src = wq; dst = wqb; j = i - N1C;
  } else {
    src = wo; dst = wob; j = i - N1C - N2C;
  }
  float4 v = ((const float4*)src)[j];
  ushort4 o;
  o.x = f2bf(v.x); o.y = f2bf(v.y); o.z = f2bf(v.z); o.w = f2bf(v.w);
  ((ushort4*)dst)[j] = o;
}

// ---------------- prep: K [B,S,H,DH] f32 -> [B,H,SP,DH] bf16, ROW-PERMUTED ------
// staged position p (within each 32-block) holds actual s-offset q*8+half*4+r
// where q=(p>>2)&3, half=(p>>4)&1, r=p&3. Zero-pad actual s >= S_.
__global__ void pack_k_kernel(const float* __restrict__ k,
                              unsigned short* __restrict__ kb) {
  int i = blockIdx.x * blockDim.x + threadIdx.x;  // group of 4 dh
  int dh4 = (i & 15) * 4;
  int j = i >> 4;
  int s = j % SP;   // staged position
  int bh = j / SP;
  if (bh >= B_ * H_) return;
  int b = bh >> 4, h = bh & 15;
  int p = s & 31;
  int src = (s & ~31) + ((p >> 2) & 3) * 8 + ((p >> 4) & 1) * 4 + (p & 3);
  ushort4 o;
  if (src < S_) {
    float4 v = *(const float4*)(k + (((size_t)(b * S_ + src) * H_ + h) * DH) + dh4);
    o.x = f2bf(v.x); o.y = f2bf(v.y); o.z = f2bf(v.z); o.w = f2bf(v.w);
  } else {
    o = make_ushort4(0, 0, 0, 0);
  }
  *(ushort4*)(kb + ((size_t)bh * SP + s) * DH + dh4) = o;
}

// ---------------- prep: V [B,S,H,DH] f32 -> transposed [B,H,DH,SP] bf16 (plain) -
__global__ void pack_vt_kernel(const float* __restrict__ v,
                               unsigned short* __restrict__ vt) {
  __shared__ unsigned short tile[64][72];  // [dh][s], padded
  int st = blockIdx.x, bh = blockIdx.y;
  int b = bh >> 4, h = bh & 15;
  int s0 = st * 64;
  int t = threadIdx.x;
  for (int i = t; i < 1024; i += 256) {
    int sl = i >> 4, dh4 = (i & 15) * 4;
    float4 val = make_float4(0.f, 0.f, 0.f, 0.f);
    if (s0 + sl < S_)
      val = *(const float4*)(v + ((size_t)((b * S_ + s0 + sl) * H_ + h)) * DH + dh4);
    tile[dh4 + 0][sl] = f2bf(val.x);
    tile[dh4 + 1][sl] = f2bf(val.y);
    tile[dh4 + 2][sl] = f2bf(val.z);
    tile[dh4 + 3][sl] = f2bf(val.w);
  }
  __syncthreads();
  for (int i = t; i < 1024; i += 256) {
    int d = i >> 4, s4 = (i & 15) * 4;
    ushort4 o;
    o.x = tile[d][s4]; o.y = tile[d][s4 + 1]; o.z = tile[d][s4 + 2]; o.w = tile[d][s4 + 3];
    *(ushort4*)(vt + ((size_t)bh * DH + d) * SP + s0 + s4) = o;
  }
}

// ---------------- bf16 GEMM  C[m,n] = sum_k A[m,k]*B[n,k]  (+bias epilogues) -----
// epi=0: qs output bf16, (val+bias)*SCALE2 (log2e folded), permuted to [B,H,T,DH]
// epi=1: fp32 output, val+bias, row-major [M,1024]
#define BK 32
#define ASTR 40
__global__ __launch_bounds__(256) void gemm_bt(const unsigned short* __restrict__ A,
                                               const unsigned short* __restrict__ Bm,
                                               const float* __restrict__ bias,
                                               void* __restrict__ outp, int epi) {
  __shared__ unsigned short As[128 * ASTR];
  __shared__ unsigned short Bs[128 * ASTR];
  const int K = 1024;
  int t = threadIdx.x;
  int m0 = blockIdx.y * 128, n0 = blockIdx.x * 128;
  int w = t >> 6, lane = t & 63, quad = lane >> 4, l16 = lane & 15;
  int mw = (w & 1) * 64, nw = (w >> 1) * 64;
  int lrow = t >> 2, lcol = (t & 3) * 8;

  const unsigned short* Ag = A + (size_t)(m0 + lrow) * K + lcol;
  const unsigned short* Bg = Bm + (size_t)(n0 + lrow) * K + lcol;

  floatx4 acc[4][4];
#pragma unroll
  for (int i = 0; i < 4; i++)
#pragma unroll
    for (int j = 0; j < 4; j++) {
      floatx4 z = {0.f, 0.f, 0.f, 0.f};
      acc[i][j] = z;
    }

  int4 a0 = *(const int4*)(Ag);
  int4 a1 = *(const int4*)(Ag + (size_t)64 * K);
  int4 b0 = *(const int4*)(Bg);
  int4 b1 = *(const int4*)(Bg + (size_t)64 * K);

  for (int kt = 0; kt < K / BK; kt++) {
    __syncthreads();
    *(int4*)&As[lrow * ASTR + lcol] = a0;
    *(int4*)&As[(lrow + 64) * ASTR + lcol] = a1;
    *(int4*)&Bs[lrow * ASTR + lcol] = b0;
    *(int4*)&Bs[(lrow + 64) * ASTR + lcol] = b1;
    __syncthreads();
    if (kt + 1 < K / BK) {
      a0 = *(const int4*)(Ag + (kt + 1) * BK);
      a1 = *(const int4*)(Ag + (size_t)64 * K + (kt + 1) * BK);
      b0 = *(const int4*)(Bg + (kt + 1) * BK);
      b1 = *(const int4*)(Bg + (size_t)64 * K + (kt + 1) * BK);
    }
    short8 af[4], bf[4];
#pragma unroll
    for (int mi = 0; mi < 4; mi++)
      af[mi] = *(const short8*)&As[(mw + mi * 16 + l16) * ASTR + quad * 8];
#pragma unroll
    for (int ni = 0; ni < 4; ni++)
      bf[ni] = *(const short8*)&Bs[(nw + ni * 16 + l16) * ASTR + quad * 8];
#pragma unroll
    for (int mi = 0; mi < 4; mi++)
#pragma unroll
      for (int ni = 0; ni < 4; ni++)
        acc[mi][ni] = mfma16(af[mi], bf[ni], acc[mi][ni]);
  }

#pragma unroll
  for (int mi = 0; mi < 4; mi++)
#pragma unroll
    for (int ni = 0; ni < 4; ni++) {
      int row = m0 + mw + mi * 16 + quad * 4;
      int col = n0 + nw + ni * 16 + l16;
      float bcol = bias[col];
#pragma unroll
      for (int r = 0; r < 4; r++) {
        float val = acc[mi][ni][r] + bcol;
        int rr = row + r;
        if (epi == 0) {
          int b = rr >> 10, tt = rr & 1023, h = col >> 6, dh = col & 63;
          ((unsigned short*)outp)[(((size_t)(b * 16 + h) * 1024) + tt) * 64 + dh] =
              f2bf(val * SCALE2_);
        } else {
          ((float*)outp)[(size_t)rr * 1024 + col] = val;
        }
      }
    }
}

// ---------------- fused flash attention, Sc^T scheme, 8-wave blocks ----------
// grid (T/128, B*H), block 512 (8 waves); wave owns 16 t-columns.
// Scores computed transposed: C col = t (lane), row = staged s (quad*4+reg).
// K staged row-permuted so P fragments re-pack in-lane as PV B-operand.
// Softmax in base-2 domain (log2e folded into q scale).
// launch_bounds (512,6): VGPR cap ~85 — kernel needs ~56 live; (512,8)'s cap
// of 64 forced allocator to 32 + scratch spills (R3: WRITE_SIZE 452 MB).
__global__ __launch_bounds__(512, 6) void attn_kernel(
    const unsigned short* __restrict__ qs, const unsigned short* __restrict__ kb,
    const unsigned short* __restrict__ vt, unsigned short* __restrict__ ob) {
  __shared__ unsigned short Ks[128 * 72];   // [staged s][dh] padded
  __shared__ unsigned short Vs[64 * 136];   // [dh][s] padded (plain order)
  int ttile = blockIdx.x, bh = blockIdx.y;
  int b = bh >> 4, h = bh & 15;
  int t = threadIdx.x, w = t >> 6, lane = t & 63, quad = lane >> 4, l16 = lane & 15;

  // Q as B-operand: n = t = l16, k(dh) = quad*8 + j
  const unsigned short* qp =
      qs + ((size_t)bh * T_ + ttile * 128 + w * 16 + l16) * DH + quad * 8;
  short8 qa0 = *(const short8*)(qp);
  short8 qa1 = *(const short8*)(qp + 32);

  const unsigned short* kbase = kb + (size_t)bh * SP * DH;
  const unsigned short* vbase = vt + (size_t)bh * DH * SP;

  floatx4 o[4];  // O^T acc: col=t(l16), row = db*16 + quad*4 + r (= dh)
#pragma unroll
  for (int i = 0; i < 4; i++) {
    floatx4 z = {0.f, 0.f, 0.f, 0.f};
    o[i] = z;
  }
  float mrow = -1e30f, lrow = 0.f;  // per-lane: this lane's t-row state (base-2)

  for (int s0 = 0; s0 < SP; s0 += 128) {
    __syncthreads();
    {
      const int4* src = (const int4*)(kbase + (size_t)s0 * DH);
#pragma unroll
      for (int i = t; i < 128 * DH / 8; i += 512) {
        int row = i >> 3, c = i & 7;
        *(int4*)&Ks[row * 72 + c * 8] = src[i];
      }
#pragma unroll
      for (int i = t; i < 64 * 128 / 8; i += 512) {
        int d = i >> 4, c = i & 15;
        *(int4*)&Vs[d * 136 + c * 8] = *(const int4*)(vbase + (size_t)d * SP + s0 + c * 8);
      }
    }
    __syncthreads();

    // Sc^T: per lane 32 staged-s values of its own t-row
    floatx4 sc[8];
#pragma unroll
    for (int nb = 0; nb < 8; nb++) {
      short8 k0 = *(const short8*)&Ks[(nb * 16 + l16) * 72 + quad * 8];
      short8 k1 = *(const short8*)&Ks[(nb * 16 + l16) * 72 + 32 + quad * 8];
      floatx4 a = {0.f, 0.f, 0.f, 0.f};
      a = mfma16(k0, qa0, a);
      a = mfma16(k1, qa1, a);
      sc[nb] = a;
    }
    if (s0 + 128 > S_) {  // mask padded actual-s (last tile only)
#pragma unroll
      for (int nb = 0; nb < 8; nb++)
#pragma unroll
        for (int r = 0; r < 4; r++) {
          int s_act = s0 + (nb >> 1) * 32 + quad * 8 + (nb & 1) * 4 + r;
          if (s_act >= S_) sc[nb][r] = -1e30f;
        }
    }

    // online softmax (base 2): in-lane over 32 + 2 shfl across quads
    float mx = -1e30f;
#pragma unroll
    for (int nb = 0; nb < 8; nb++) {
      float a0m = fmaxf(sc[nb][0], sc[nb][1]);
      float a1m = fmaxf(sc[nb][2], sc[nb][3]);
      mx = fmaxf(mx, fmaxf(a0m, a1m));
    }
    mx = fmaxf(mx, __shfl_xor(mx, 16));
    mx = fmaxf(mx, __shfl_xor(mx, 32));
    float mnew = fmaxf(mrow, mx);
    float alpha = exp2f(mrow - mnew);
    mrow = mnew;
    float rs = 0.f;
#pragma unroll
    for (int nb = 0; nb < 8; nb++) {
#pragma unroll
      for (int r = 0; r < 4; r++) {
        float p = exp2f(sc[nb][r] - mnew);
        sc[nb][r] = p;
        rs += p;
      }
    }
    rs += __shfl_xor(rs, 16);
    rs += __shfl_xor(rs, 32);
    lrow = lrow * alpha + rs;
#pragma unroll
    for (int db = 0; db < 4; db++) {
      o[db][0] *= alpha; o[db][1] *= alpha; o[db][2] *= alpha; o[db][3] *= alpha;
    }

    // PV: O^T[d][t] += V^T(A) * P(B).  chunk c covers staged s = c*32..c*32+31
#pragma unroll
    for (int c = 0; c < 4; c++) {
      union { short8 v; __hip_bfloat162 h[4]; } pk;
      pk.h[0] = __float22bfloat162_rn(make_float2(sc[2 * c][0], sc[2 * c][1]));
      pk.h[1] = __float22bfloat162_rn(make_float2(sc[2 * c][2], sc[2 * c][3]));
      pk.h[2] = __float22bfloat162_rn(make_float2(sc[2 * c + 1][0], sc[2 * c + 1][1]));
      pk.h[3] = __float22bfloat162_rn(make_float2(sc[2 * c + 1][2], sc[2 * c + 1][3]));
#pragma unroll
      for (int db = 0; db < 4; db++) {
        short8 vf = *(const short8*)&Vs[(db * 16 + l16) * 136 + c * 32 + quad * 8];
        o[db] = mfma16(vf, pk.v, o[db]);
      }
    }
  }

  float inv = 1.0f / lrow;
  int tg = ttile * 128 + w * 16 + l16;
#pragma unroll
  for (int db = 0; db < 4; db++) {
    int dh = db * 16 + quad * 4;
    union { ushort4 s4; __hip_bfloat162 h[2]; } st;
    st.h[0] = __float22bfloat162_rn(make_float2(o[db][0] * inv, o[db][1] * inv));
    st.h[1] = __float22bfloat162_rn(make_float2(o[db][2] * inv, o[db][3] * inv));
    *(ushort4*)(ob + ((size_t)(b * T_ + tg) * H_ + h) * DH + dh) = st.s4;
  }
}

extern "C" void kernel_launch(void* const* d_in, const int* in_sizes, int n_in,
                              void* d_out, int out_size, void* d_ws, size_t ws_size,
                              hipStream_t stream) {
  const float* x  = (const float*)d_in[0];
  const float* k  = (const float*)d_in[1];
  const float* v  = (const float*)d_in[2];
  const float* wq = (const float*)d_in[3];
  const float* bq = (const float*)d_in[4];
  const float* wo = (const float*)d_in[5];
  const float* bo = (const float*)d_in[6];
  float* out = (float*)d_out;

  char* ws = (char*)d_ws;
  unsigned short* xb  = (unsigned short*)(ws + 0);
  unsigned short* wqb = (unsigned short*)(ws + 16777216);
  unsigned short* wob = (unsigned short*)(ws + 18874368);
  unsigned short* kbp = (unsigned short*)(ws + 20971520);
  unsigned short* vtp = (unsigned short*)(ws + 46137344);
  unsigned short* qsp = (unsigned short*)(ws + 71303168);
  unsigned short* obp = (unsigned short*)(ws + 88080384);

  {
    int blocks = (N1C + 2 * N2C) / 256;
    cast3_kernel<<<blocks, 256, 0, stream>>>(x, wq, wo, xb, wqb, wob);
  }
  {
    int groups = B_ * H_ * SP * 16;
    pack_k_kernel<<<groups / 256, 256, 0, stream>>>(k, kbp);
    pack_vt_kernel<<<dim3(SP / 64, B_ * H_), 256, 0, stream>>>(v, vtp);
  }
  gemm_bt<<<dim3(D_ / 128, B_ * T_ / 128), 256, 0, stream>>>(xb, wqb, bq, qsp, 0);
  attn_kernel<<<dim3(T_ / 128, B_ * H_), 512, 0, stream>>>(qsp, kbp, vtp, obp);
  gemm_bt<<<dim3(D_ / 128, B_ * T_ / 128), 256, 0, stream>>>(obp, wob, bo, out, 1);
}

// Round 5
// 361.217 us; speedup vs baseline: 1.3028x; 1.1177x over previous
//
#include <hip/hip_runtime.h>
#include <hip/hip_bf16.h>

typedef __attribute__((ext_vector_type(8))) short short8;
typedef __attribute__((ext_vector_type(4))) float floatx4;

#define B_ 8
#define T_ 1024
#define S_ 1500
#define SP 1536
#define D_ 1024
#define H_ 16
#define DH 64
// q-scale with log2(e) folded in: exp(x) = exp2(x * log2e)
#define SCALE2_ 0.1803368801111244f

__device__ __forceinline__ unsigned short f2bf(float f) {
  unsigned u = __float_as_uint(f);
  u += 0x7fffu + ((u >> 16) & 1u);
  return (unsigned short)(u >> 16);
}

__device__ __forceinline__ floatx4 mfma16(short8 a, short8 b, floatx4 c) {
  return __builtin_amdgcn_mfma_f32_16x16x32_bf16(a, b, c, 0, 0, 0);
}

// ---------------- prep: fused fp32 -> bf16 cast for x, wq, wo ----------------
#define N1C (B_ * T_ * D_ / 4)
#define N2C (D_ * D_ / 4)
__global__ void cast3_kernel(const float* __restrict__ x, const float* __restrict__ wq,
                             const float* __restrict__ wo, unsigned short* __restrict__ xb,
                             unsigned short* __restrict__ wqb,
                             unsigned short* __restrict__ wob) {
  int i = blockIdx.x * blockDim.x + threadIdx.x;
  const float* src;
  unsigned short* dst;
  int j;
  if (i < N1C) {
    src = x; dst = xb; j = i;
  } else if (i < N1C + N2C) {
    src = wq; dst = wqb; j = i - N1C;
  } else {
    src = wo; dst = wob; j = i - N1C - N2C;
  }
  float4 v = ((const float4*)src)[j];
  ushort4 o;
  o.x = f2bf(v.x); o.y = f2bf(v.y); o.z = f2bf(v.z); o.w = f2bf(v.w);
  ((ushort4*)dst)[j] = o;
}

// ---------------- prep: K [B,S,H,DH] f32 -> [B,H,SP,DH] bf16, ROW-PERMUTED ------
// staged position p (within each 32-block) holds actual s-offset q*8+half*4+r
// where q=(p>>2)&3, half=(p>>4)&1, r=p&3. Zero-pad actual s >= S_.
__global__ void pack_k_kernel(const float* __restrict__ k,
                              unsigned short* __restrict__ kb) {
  int i = blockIdx.x * blockDim.x + threadIdx.x;  // group of 4 dh
  int dh4 = (i & 15) * 4;
  int j = i >> 4;
  int s = j % SP;   // staged position
  int bh = j / SP;
  if (bh >= B_ * H_) return;
  int b = bh >> 4, h = bh & 15;
  int p = s & 31;
  int src = (s & ~31) + ((p >> 2) & 3) * 8 + ((p >> 4) & 1) * 4 + (p & 3);
  ushort4 o;
  if (src < S_) {
    float4 v = *(const float4*)(k + (((size_t)(b * S_ + src) * H_ + h) * DH) + dh4);
    o.x = f2bf(v.x); o.y = f2bf(v.y); o.z = f2bf(v.z); o.w = f2bf(v.w);
  } else {
    o = make_ushort4(0, 0, 0, 0);
  }
  *(ushort4*)(kb + ((size_t)bh * SP + s) * DH + dh4) = o;
}

// ---------------- prep: V [B,S,H,DH] f32 -> transposed [B,H,DH,SP] bf16 (plain) -
__global__ void pack_vt_kernel(const float* __restrict__ v,
                               unsigned short* __restrict__ vt) {
  __shared__ unsigned short tile[64][72];  // [dh][s], padded
  int st = blockIdx.x, bh = blockIdx.y;
  int b = bh >> 4, h = bh & 15;
  int s0 = st * 64;
  int t = threadIdx.x;
  for (int i = t; i < 1024; i += 256) {
    int sl = i >> 4, dh4 = (i & 15) * 4;
    float4 val = make_float4(0.f, 0.f, 0.f, 0.f);
    if (s0 + sl < S_)
      val = *(const float4*)(v + ((size_t)((b * S_ + s0 + sl) * H_ + h)) * DH + dh4);
    tile[dh4 + 0][sl] = f2bf(val.x);
    tile[dh4 + 1][sl] = f2bf(val.y);
    tile[dh4 + 2][sl] = f2bf(val.z);
    tile[dh4 + 3][sl] = f2bf(val.w);
  }
  __syncthreads();
  for (int i = t; i < 1024; i += 256) {
    int d = i >> 4, s4 = (i & 15) * 4;
    ushort4 o;
    o.x = tile[d][s4]; o.y = tile[d][s4 + 1]; o.z = tile[d][s4 + 2]; o.w = tile[d][s4 + 3];
    *(ushort4*)(vt + ((size_t)bh * DH + d) * SP + s0 + s4) = o;
  }
}

// ---------------- bf16 GEMM  C[m,n] = sum_k A[m,k]*B[n,k]  (+bias epilogues) -----
// epi=0: qs output bf16, (val+bias)*SCALE2 (log2e folded), permuted to [B,H,T,DH]
// epi=1: fp32 output, val+bias, row-major [M,1024]
#define BK 32
#define ASTR 40
__global__ __launch_bounds__(256) void gemm_bt(const unsigned short* __restrict__ A,
                                               const unsigned short* __restrict__ Bm,
                                               const float* __restrict__ bias,
                                               void* __restrict__ outp, int epi) {
  __shared__ unsigned short As[128 * ASTR];
  __shared__ unsigned short Bs[128 * ASTR];
  const int K = 1024;
  int t = threadIdx.x;
  int m0 = blockIdx.y * 128, n0 = blockIdx.x * 128;
  int w = t >> 6, lane = t & 63, quad = lane >> 4, l16 = lane & 15;
  int mw = (w & 1) * 64, nw = (w >> 1) * 64;
  int lrow = t >> 2, lcol = (t & 3) * 8;

  const unsigned short* Ag = A + (size_t)(m0 + lrow) * K + lcol;
  const unsigned short* Bg = Bm + (size_t)(n0 + lrow) * K + lcol;

  floatx4 acc[4][4];
#pragma unroll
  for (int i = 0; i < 4; i++)
#pragma unroll
    for (int j = 0; j < 4; j++) {
      floatx4 z = {0.f, 0.f, 0.f, 0.f};
      acc[i][j] = z;
    }

  int4 a0 = *(const int4*)(Ag);
  int4 a1 = *(const int4*)(Ag + (size_t)64 * K);
  int4 b0 = *(const int4*)(Bg);
  int4 b1 = *(const int4*)(Bg + (size_t)64 * K);

  for (int kt = 0; kt < K / BK; kt++) {
    __syncthreads();
    *(int4*)&As[lrow * ASTR + lcol] = a0;
    *(int4*)&As[(lrow + 64) * ASTR + lcol] = a1;
    *(int4*)&Bs[lrow * ASTR + lcol] = b0;
    *(int4*)&Bs[(lrow + 64) * ASTR + lcol] = b1;
    __syncthreads();
    if (kt + 1 < K / BK) {
      a0 = *(const int4*)(Ag + (kt + 1) * BK);
      a1 = *(const int4*)(Ag + (size_t)64 * K + (kt + 1) * BK);
      b0 = *(const int4*)(Bg + (kt + 1) * BK);
      b1 = *(const int4*)(Bg + (size_t)64 * K + (kt + 1) * BK);
    }
    short8 af[4], bf[4];
#pragma unroll
    for (int mi = 0; mi < 4; mi++)
      af[mi] = *(const short8*)&As[(mw + mi * 16 + l16) * ASTR + quad * 8];
#pragma unroll
    for (int ni = 0; ni < 4; ni++)
      bf[ni] = *(const short8*)&Bs[(nw + ni * 16 + l16) * ASTR + quad * 8];
#pragma unroll
    for (int mi = 0; mi < 4; mi++)
#pragma unroll
      for (int ni = 0; ni < 4; ni++)
        acc[mi][ni] = mfma16(af[mi], bf[ni], acc[mi][ni]);
  }

#pragma unroll
  for (int mi = 0; mi < 4; mi++)
#pragma unroll
    for (int ni = 0; ni < 4; ni++) {
      int row = m0 + mw + mi * 16 + quad * 4;
      int col = n0 + nw + ni * 16 + l16;
      float bcol = bias[col];
#pragma unroll
      for (int r = 0; r < 4; r++) {
        float val = acc[mi][ni][r] + bcol;
        int rr = row + r;
        if (epi == 0) {
          int b = rr >> 10, tt = rr & 1023, h = col >> 6, dh = col & 63;
          ((unsigned short*)outp)[(((size_t)(b * 16 + h) * 1024) + tt) * 64 + dh] =
              f2bf(val * SCALE2_);
        } else {
          ((float*)outp)[(size_t)rr * 1024 + col] = val;
        }
      }
    }
}

// ---------------- fused flash attention, Sc^T scheme, 8-wave blocks ----------
// grid (T/128, B*H), block 512 (8 waves); wave owns 16 t-columns.
// Scores computed transposed: C col = t (lane), row = staged s (quad*4+reg).
// K staged row-permuted so P fragments re-pack in-lane as PV B-operand.
// Softmax in base-2 domain (log2e folded into q scale).
// launch_bounds (512,4): reg cap 128. Kernel needs ~88 total regs on the
// unified VGPR/AGPR file (sc 32 + o 16 + q 8 + misc ~30). Caps of 64 (R3)
// and ~85 (R4) both forced scratch spills (WRITE_SIZE 452/210 MB).
__global__ __launch_bounds__(512, 4) void attn_kernel(
    const unsigned short* __restrict__ qs, const unsigned short* __restrict__ kb,
    const unsigned short* __restrict__ vt, unsigned short* __restrict__ ob) {
  __shared__ unsigned short Ks[128 * 72];   // [staged s][dh] padded
  __shared__ unsigned short Vs[64 * 136];   // [dh][s] padded (plain order)
  int ttile = blockIdx.x, bh = blockIdx.y;
  int b = bh >> 4, h = bh & 15;
  int t = threadIdx.x, w = t >> 6, lane = t & 63, quad = lane >> 4, l16 = lane & 15;

  // Q as B-operand: n = t = l16, k(dh) = quad*8 + j
  const unsigned short* qp =
      qs + ((size_t)bh * T_ + ttile * 128 + w * 16 + l16) * DH + quad * 8;
  short8 qa0 = *(const short8*)(qp);
  short8 qa1 = *(const short8*)(qp + 32);

  const unsigned short* kbase = kb + (size_t)bh * SP * DH;
  const unsigned short* vbase = vt + (size_t)bh * DH * SP;

  floatx4 o[4];  // O^T acc: col=t(l16), row = db*16 + quad*4 + r (= dh)
#pragma unroll
  for (int i = 0; i < 4; i++) {
    floatx4 z = {0.f, 0.f, 0.f, 0.f};
    o[i] = z;
  }
  float mrow = -1e30f, lrow = 0.f;  // per-lane: this lane's t-row state (base-2)

  for (int s0 = 0; s0 < SP; s0 += 128) {
    __syncthreads();
    {
      const int4* src = (const int4*)(kbase + (size_t)s0 * DH);
#pragma unroll
      for (int i = t; i < 128 * DH / 8; i += 512) {
        int row = i >> 3, c = i & 7;
        *(int4*)&Ks[row * 72 + c * 8] = src[i];
      }
#pragma unroll
      for (int i = t; i < 64 * 128 / 8; i += 512) {
        int d = i >> 4, c = i & 15;
        *(int4*)&Vs[d * 136 + c * 8] = *(const int4*)(vbase + (size_t)d * SP + s0 + c * 8);
      }
    }
    __syncthreads();

    // Sc^T: per lane 32 staged-s values of its own t-row
    floatx4 sc[8];
#pragma unroll
    for (int nb = 0; nb < 8; nb++) {
      short8 k0 = *(const short8*)&Ks[(nb * 16 + l16) * 72 + quad * 8];
      short8 k1 = *(const short8*)&Ks[(nb * 16 + l16) * 72 + 32 + quad * 8];
      floatx4 a = {0.f, 0.f, 0.f, 0.f};
      a = mfma16(k0, qa0, a);
      a = mfma16(k1, qa1, a);
      sc[nb] = a;
    }
    if (s0 + 128 > S_) {  // mask padded actual-s (last tile only)
#pragma unroll
      for (int nb = 0; nb < 8; nb++)
#pragma unroll
        for (int r = 0; r < 4; r++) {
          int s_act = s0 + (nb >> 1) * 32 + quad * 8 + (nb & 1) * 4 + r;
          if (s_act >= S_) sc[nb][r] = -1e30f;
        }
    }

    // online softmax (base 2): in-lane over 32 + 2 shfl across quads
    float mx = -1e30f;
#pragma unroll
    for (int nb = 0; nb < 8; nb++) {
      float a0m = fmaxf(sc[nb][0], sc[nb][1]);
      float a1m = fmaxf(sc[nb][2], sc[nb][3]);
      mx = fmaxf(mx, fmaxf(a0m, a1m));
    }
    mx = fmaxf(mx, __shfl_xor(mx, 16));
    mx = fmaxf(mx, __shfl_xor(mx, 32));
    float mnew = fmaxf(mrow, mx);
    float alpha = exp2f(mrow - mnew);
    mrow = mnew;
    float rs = 0.f;
#pragma unroll
    for (int nb = 0; nb < 8; nb++) {
#pragma unroll
      for (int r = 0; r < 4; r++) {
        float p = exp2f(sc[nb][r] - mnew);
        sc[nb][r] = p;
        rs += p;
      }
    }
    rs += __shfl_xor(rs, 16);
    rs += __shfl_xor(rs, 32);
    lrow = lrow * alpha + rs;
#pragma unroll
    for (int db = 0; db < 4; db++) {
      o[db][0] *= alpha; o[db][1] *= alpha; o[db][2] *= alpha; o[db][3] *= alpha;
    }

    // PV: O^T[d][t] += V^T(A) * P(B).  chunk c covers staged s = c*32..c*32+31
#pragma unroll
    for (int c = 0; c < 4; c++) {
      union { short8 v; __hip_bfloat162 h[4]; } pk;
      pk.h[0] = __float22bfloat162_rn(make_float2(sc[2 * c][0], sc[2 * c][1]));
      pk.h[1] = __float22bfloat162_rn(make_float2(sc[2 * c][2], sc[2 * c][3]));
      pk.h[2] = __float22bfloat162_rn(make_float2(sc[2 * c + 1][0], sc[2 * c + 1][1]));
      pk.h[3] = __float22bfloat162_rn(make_float2(sc[2 * c + 1][2], sc[2 * c + 1][3]));
#pragma unroll
      for (int db = 0; db < 4; db++) {
        short8 vf = *(const short8*)&Vs[(db * 16 + l16) * 136 + c * 32 + quad * 8];
        o[db] = mfma16(vf, pk.v, o[db]);
      }
    }
  }

  float inv = 1.0f / lrow;
  int tg = ttile * 128 + w * 16 + l16;
#pragma unroll
  for (int db = 0; db < 4; db++) {
    int dh = db * 16 + quad * 4;
    union { ushort4 s4; __hip_bfloat162 h[2]; } st;
    st.h[0] = __float22bfloat162_rn(make_float2(o[db][0] * inv, o[db][1] * inv));
    st.h[1] = __float22bfloat162_rn(make_float2(o[db][2] * inv, o[db][3] * inv));
    *(ushort4*)(ob + ((size_t)(b * T_ + tg) * H_ + h) * DH + dh) = st.s4;
  }
}

extern "C" void kernel_launch(void* const* d_in, const int* in_sizes, int n_in,
                              void* d_out, int out_size, void* d_ws, size_t ws_size,
                              hipStream_t stream) {
  const float* x  = (const float*)d_in[0];
  const float* k  = (const float*)d_in[1];
  const float* v  = (const float*)d_in[2];
  const float* wq = (const float*)d_in[3];
  const float* bq = (const float*)d_in[4];
  const float* wo = (const float*)d_in[5];
  const float* bo = (const float*)d_in[6];
  float* out = (float*)d_out;

  char* ws = (char*)d_ws;
  unsigned short* xb  = (unsigned short*)(ws + 0);
  unsigned short* wqb = (unsigned short*)(ws + 16777216);
  unsigned short* wob = (unsigned short*)(ws + 18874368);
  unsigned short* kbp = (unsigned short*)(ws + 20971520);
  unsigned short* vtp = (unsigned short*)(ws + 46137344);
  unsigned short* qsp = (unsigned short*)(ws + 71303168);
  unsigned short* obp = (unsigned short*)(ws + 88080384);

  {
    int blocks = (N1C + 2 * N2C) / 256;
    cast3_kernel<<<blocks, 256, 0, stream>>>(x, wq, wo, xb, wqb, wob);
  }
  {
    int groups = B_ * H_ * SP * 16;
    pack_k_kernel<<<groups / 256, 256, 0, stream>>>(k, kbp);
    pack_vt_kernel<<<dim3(SP / 64, B_ * H_), 256, 0, stream>>>(v, vtp);
  }
  gemm_bt<<<dim3(D_ / 128, B_ * T_ / 128), 256, 0, stream>>>(xb, wqb, bq, qsp, 0);
  attn_kernel<<<dim3(T_ / 128, B_ * H_), 512, 0, stream>>>(qsp, kbp, vtp, obp);
  gemm_bt<<<dim3(D_ / 128, B_ * T_ / 128), 256, 0, stream>>>(obp, wob, bo, out, 1);
}

// Round 6
// 346.761 us; speedup vs baseline: 1.3571x; 1.0417x over previous
//
#include <hip/hip_runtime.h>
#include <hip/hip_bf16.h>

typedef __attribute__((ext_vector_type(8))) short short8;
typedef __attribute__((ext_vector_type(4))) float floatx4;

#define B_ 8
#define T_ 1024
#define S_ 1500
#define SP 1536
#define D_ 1024
#define H_ 16
#define DH 64
// q-scale with log2(e) folded in: exp(x) = exp2(x * log2e)
#define SCALE2_ 0.1803368801111244f

__device__ __forceinline__ unsigned short f2bf(float f) {
  unsigned u = __float_as_uint(f);
  u += 0x7fffu + ((u >> 16) & 1u);
  return (unsigned short)(u >> 16);
}

__device__ __forceinline__ floatx4 mfma16(short8 a, short8 b, floatx4 c) {
  return __builtin_amdgcn_mfma_f32_16x16x32_bf16(a, b, c, 0, 0, 0);
}

// async global->LDS, 16B per lane. LDS dest = wave-uniform base + lane*16.
__device__ __forceinline__ void gload_lds16(const unsigned short* g, unsigned short* l) {
  __builtin_amdgcn_global_load_lds(
      (const __attribute__((address_space(1))) unsigned int*)g,
      (__attribute__((address_space(3))) unsigned int*)(unsigned long)(uintptr_t)l, 16, 0, 0);
}

// ---------------- prep: fused fp32 -> bf16 cast for x, wq, wo ----------------
#define N1C (B_ * T_ * D_ / 4)
#define N2C (D_ * D_ / 4)
__global__ void cast3_kernel(const float* __restrict__ x, const float* __restrict__ wq,
                             const float* __restrict__ wo, unsigned short* __restrict__ xb,
                             unsigned short* __restrict__ wqb,
                             unsigned short* __restrict__ wob) {
  int i = blockIdx.x * blockDim.x + threadIdx.x;
  const float* src;
  unsigned short* dst;
  int j;
  if (i < N1C) {
    src = x; dst = xb; j = i;
  } else if (i < N1C + N2C) {
    src = wq; dst = wqb; j = i - N1C;
  } else {
    src = wo; dst = wob; j = i - N1C - N2C;
  }
  float4 v = ((const float4*)src)[j];
  ushort4 o;
  o.x = f2bf(v.x); o.y = f2bf(v.y); o.z = f2bf(v.z); o.w = f2bf(v.w);
  ((ushort4*)dst)[j] = o;
}

// ---------------- prep: K [B,S,H,DH] f32 -> [B,H,SP,DH] bf16, ROW-PERMUTED ------
__global__ void pack_k_kernel(const float* __restrict__ k,
                              unsigned short* __restrict__ kb) {
  int i = blockIdx.x * blockDim.x + threadIdx.x;  // group of 4 dh
  int dh4 = (i & 15) * 4;
  int j = i >> 4;
  int s = j % SP;   // staged position
  int bh = j / SP;
  if (bh >= B_ * H_) return;
  int b = bh >> 4, h = bh & 15;
  int p = s & 31;
  int src = (s & ~31) + ((p >> 2) & 3) * 8 + ((p >> 4) & 1) * 4 + (p & 3);
  ushort4 o;
  if (src < S_) {
    float4 v = *(const float4*)(k + (((size_t)(b * S_ + src) * H_ + h) * DH) + dh4);
    o.x = f2bf(v.x); o.y = f2bf(v.y); o.z = f2bf(v.z); o.w = f2bf(v.w);
  } else {
    o = make_ushort4(0, 0, 0, 0);
  }
  *(ushort4*)(kb + ((size_t)bh * SP + s) * DH + dh4) = o;
}

// ---------------- prep: V [B,S,H,DH] f32 -> transposed [B,H,DH,SP] bf16 (plain) -
__global__ void pack_vt_kernel(const float* __restrict__ v,
                               unsigned short* __restrict__ vt) {
  __shared__ unsigned short tile[64][72];  // [dh][s], padded
  int st = blockIdx.x, bh = blockIdx.y;
  int b = bh >> 4, h = bh & 15;
  int s0 = st * 64;
  int t = threadIdx.x;
  for (int i = t; i < 1024; i += 256) {
    int sl = i >> 4, dh4 = (i & 15) * 4;
    float4 val = make_float4(0.f, 0.f, 0.f, 0.f);
    if (s0 + sl < S_)
      val = *(const float4*)(v + ((size_t)((b * S_ + s0 + sl) * H_ + h)) * DH + dh4);
    tile[dh4 + 0][sl] = f2bf(val.x);
    tile[dh4 + 1][sl] = f2bf(val.y);
    tile[dh4 + 2][sl] = f2bf(val.z);
    tile[dh4 + 3][sl] = f2bf(val.w);
  }
  __syncthreads();
  for (int i = t; i < 1024; i += 256) {
    int d = i >> 4, s4 = (i & 15) * 4;
    ushort4 o;
    o.x = tile[d][s4]; o.y = tile[d][s4 + 1]; o.z = tile[d][s4 + 2]; o.w = tile[d][s4 + 3];
    *(ushort4*)(vt + ((size_t)bh * DH + d) * SP + s0 + s4) = o;
  }
}

// ---------------- bf16 GEMM  C[m,n] = sum_k A[m,k]*B[n,k]  (+bias epilogues) -----
// m97-style: global_load_lds width=16 staging into UNPADDED [128][32] tiles with
// XOR chunk swizzle. Physical 16B-chunk slot pc at row r holds global chunk
// pc ^ ((r>>1)&3); fragment ds_read_b128 then lands 2 lanes/bank (free, m136).
// epi=0: qs output bf16, (val+bias)*SCALE2 (log2e folded), permuted to [B,H,T,DH]
// epi=1: fp32 output, val+bias, row-major [M,1024]
#define BK 32
__global__ __launch_bounds__(256, 4) void gemm_bt(const unsigned short* __restrict__ A,
                                                  const unsigned short* __restrict__ Bm,
                                                  const float* __restrict__ bias,
                                                  void* __restrict__ outp, int epi) {
  __shared__ unsigned short As[128 * BK];
  __shared__ unsigned short Bs[128 * BK];
  const int K = 1024;
  int t = threadIdx.x;
  int m0 = blockIdx.y * 128, n0 = blockIdx.x * 128;
  int w = t >> 6, lane = t & 63, quad = lane >> 4, l16 = lane & 15;
  int mw = (w & 1) * 64, nw = (w >> 1) * 64;

  // staging lane roles: each wave stages 16 rows per instr (lane i -> row base+i/4,
  // chunk slot i%4 which must hold global chunk g = (i%4) ^ ((row>>1)&3)
  int rloc = lane >> 2, c = lane & 3;
  int g = c ^ (((w * 16 + rloc) >> 1) & 3);  // +64 rows doesn't change ((row>>1)&3)
  const unsigned short* pa0 = A + (size_t)(m0 + w * 16 + rloc) * K + g * 8;
  const unsigned short* pa1 = pa0 + (size_t)64 * K;
  const unsigned short* pb0 = Bm + (size_t)(n0 + w * 16 + rloc) * K + g * 8;
  const unsigned short* pb1 = pb0 + (size_t)64 * K;
  unsigned short* lA0 = &As[(w * 16) * BK];
  unsigned short* lA1 = &As[(64 + w * 16) * BK];
  unsigned short* lB0 = &Bs[(w * 16) * BK];
  unsigned short* lB1 = &Bs[(64 + w * 16) * BK];

  floatx4 acc[4][4];
#pragma unroll
  for (int i = 0; i < 4; i++)
#pragma unroll
    for (int j = 0; j < 4; j++) {
      floatx4 z = {0.f, 0.f, 0.f, 0.f};
      acc[i][j] = z;
    }

  // fragment read offsets (swizzled)
  int arow = mw + l16;  // + mi*16
  int brow = nw + l16;  // + ni*16

  for (int kt = 0; kt < K / BK; kt++) {
    __syncthreads();  // previous tile's reads complete
    gload_lds16(pa0 + kt * BK, lA0);
    gload_lds16(pa1 + kt * BK, lA1);
    gload_lds16(pb0 + kt * BK, lB0);
    gload_lds16(pb1 + kt * BK, lB1);
    __syncthreads();  // drains vmcnt -> staged data visible

    short8 af[4], bf[4];
#pragma unroll
    for (int mi = 0; mi < 4; mi++) {
      int r = arow + mi * 16;
      int pc = quad ^ ((r >> 1) & 3);
      af[mi] = *(const short8*)&As[r * BK + pc * 8];
    }
#pragma unroll
    for (int ni = 0; ni < 4; ni++) {
      int r = brow + ni * 16;
      int pc = quad ^ ((r >> 1) & 3);
      bf[ni] = *(const short8*)&Bs[r * BK + pc * 8];
    }
#pragma unroll
    for (int mi = 0; mi < 4; mi++)
#pragma unroll
      for (int ni = 0; ni < 4; ni++)
        acc[mi][ni] = mfma16(af[mi], bf[ni], acc[mi][ni]);
  }

#pragma unroll
  for (int mi = 0; mi < 4; mi++)
#pragma unroll
    for (int ni = 0; ni < 4; ni++) {
      int row = m0 + mw + mi * 16 + quad * 4;
      int col = n0 + nw + ni * 16 + l16;
      float bcol = bias[col];
#pragma unroll
      for (int r = 0; r < 4; r++) {
        float val = acc[mi][ni][r] + bcol;
        int rr = row + r;
        if (epi == 0) {
          int b = rr >> 10, tt = rr & 1023, h = col >> 6, dh = col & 63;
          ((unsigned short*)outp)[(((size_t)(b * 16 + h) * 1024) + tt) * 64 + dh] =
              f2bf(val * SCALE2_);
        } else {
          ((float*)outp)[(size_t)rr * 1024 + col] = val;
        }
      }
    }
}

// ---------------- fused flash attention, Sc^T scheme, 8-wave blocks ----------
// grid (T/128, B*H), block 512 (8 waves); wave owns 16 t-columns.
// Scores computed transposed: C col = t (lane), row = staged s (quad*4+reg).
// K staged row-permuted so P fragments re-pack in-lane as PV B-operand.
// Softmax in base-2 domain (log2e folded into q scale).
// launch_bounds (512,4): reg cap 128; smaller caps spilled (R3/R4).
__global__ __launch_bounds__(512, 4) void attn_kernel(
    const unsigned short* __restrict__ qs, const unsigned short* __restrict__ kb,
    const unsigned short* __restrict__ vt, unsigned short* __restrict__ ob) {
  __shared__ unsigned short Ks[128 * 72];   // [staged s][dh] padded
  __shared__ unsigned short Vs[64 * 136];   // [dh][s] padded (plain order)
  int ttile = blockIdx.x, bh = blockIdx.y;
  int b = bh >> 4, h = bh & 15;
  int t = threadIdx.x, w = t >> 6, lane = t & 63, quad = lane >> 4, l16 = lane & 15;

  // Q as B-operand: n = t = l16, k(dh) = quad*8 + j
  const unsigned short* qp =
      qs + ((size_t)bh * T_ + ttile * 128 + w * 16 + l16) * DH + quad * 8;
  short8 qa0 = *(const short8*)(qp);
  short8 qa1 = *(const short8*)(qp + 32);

  const unsigned short* kbase = kb + (size_t)bh * SP * DH;
  const unsigned short* vbase = vt + (size_t)bh * DH * SP;

  floatx4 o[4];  // O^T acc: col=t(l16), row = db*16 + quad*4 + r (= dh)
#pragma unroll
  for (int i = 0; i < 4; i++) {
    floatx4 z = {0.f, 0.f, 0.f, 0.f};
    o[i] = z;
  }
  float mrow = -1e30f, lrow = 0.f;  // per-lane: this lane's t-row state (base-2)

  for (int s0 = 0; s0 < SP; s0 += 128) {
    __syncthreads();
    {
      const int4* src = (const int4*)(kbase + (size_t)s0 * DH);
#pragma unroll
      for (int i = t; i < 128 * DH / 8; i += 512) {
        int row = i >> 3, c = i & 7;
        *(int4*)&Ks[row * 72 + c * 8] = src[i];
      }
#pragma unroll
      for (int i = t; i < 64 * 128 / 8; i += 512) {
        int d = i >> 4, c = i & 15;
        *(int4*)&Vs[d * 136 + c * 8] = *(const int4*)(vbase + (size_t)d * SP + s0 + c * 8);
      }
    }
    __syncthreads();

    // Sc^T: per lane 32 staged-s values of its own t-row
    floatx4 sc[8];
#pragma unroll
    for (int nb = 0; nb < 8; nb++) {
      short8 k0 = *(const short8*)&Ks[(nb * 16 + l16) * 72 + quad * 8];
      short8 k1 = *(const short8*)&Ks[(nb * 16 + l16) * 72 + 32 + quad * 8];
      floatx4 a = {0.f, 0.f, 0.f, 0.f};
      a = mfma16(k0, qa0, a);
      a = mfma16(k1, qa1, a);
      sc[nb] = a;
    }
    if (s0 + 128 > S_) {  // mask padded actual-s (last tile only)
#pragma unroll
      for (int nb = 0; nb < 8; nb++)
#pragma unroll
        for (int r = 0; r < 4; r++) {
          int s_act = s0 + (nb >> 1) * 32 + quad * 8 + (nb & 1) * 4 + r;
          if (s_act >= S_) sc[nb][r] = -1e30f;
        }
    }

    // online softmax (base 2): in-lane over 32 + 2 shfl across quads
    float mx = -1e30f;
#pragma unroll
    for (int nb = 0; nb < 8; nb++) {
      float a0m = fmaxf(sc[nb][0], sc[nb][1]);
      float a1m = fmaxf(sc[nb][2], sc[nb][3]);
      mx = fmaxf(mx, fmaxf(a0m, a1m));
    }
    mx = fmaxf(mx, __shfl_xor(mx, 16));
    mx = fmaxf(mx, __shfl_xor(mx, 32));
    float mnew = fmaxf(mrow, mx);
    float alpha = exp2f(mrow - mnew);
    mrow = mnew;
    float rs = 0.f;
#pragma unroll
    for (int nb = 0; nb < 8; nb++) {
#pragma unroll
      for (int r = 0; r < 4; r++) {
        float p = exp2f(sc[nb][r] - mnew);
        sc[nb][r] = p;
        rs += p;
      }
    }
    rs += __shfl_xor(rs, 16);
    rs += __shfl_xor(rs, 32);
    lrow = lrow * alpha + rs;
#pragma unroll
    for (int db = 0; db < 4; db++) {
      o[db][0] *= alpha; o[db][1] *= alpha; o[db][2] *= alpha; o[db][3] *= alpha;
    }

    // PV: O^T[d][t] += V^T(A) * P(B).  chunk c covers staged s = c*32..c*32+31
#pragma unroll
    for (int c = 0; c < 4; c++) {
      union { short8 v; __hip_bfloat162 h[4]; } pk;
      pk.h[0] = __float22bfloat162_rn(make_float2(sc[2 * c][0], sc[2 * c][1]));
      pk.h[1] = __float22bfloat162_rn(make_float2(sc[2 * c][2], sc[2 * c][3]));
      pk.h[2] = __float22bfloat162_rn(make_float2(sc[2 * c + 1][0], sc[2 * c + 1][1]));
      pk.h[3] = __float22bfloat162_rn(make_float2(sc[2 * c + 1][2], sc[2 * c + 1][3]));
#pragma unroll
      for (int db = 0; db < 4; db++) {
        short8 vf = *(const short8*)&Vs[(db * 16 + l16) * 136 + c * 32 + quad * 8];
        o[db] = mfma16(vf, pk.v, o[db]);
      }
    }
  }

  float inv = 1.0f / lrow;
  int tg = ttile * 128 + w * 16 + l16;
#pragma unroll
  for (int db = 0; db < 4; db++) {
    int dh = db * 16 + quad * 4;
    union { ushort4 s4; __hip_bfloat162 h[2]; } st;
    st.h[0] = __float22bfloat162_rn(make_float2(o[db][0] * inv, o[db][1] * inv));
    st.h[1] = __float22bfloat162_rn(make_float2(o[db][2] * inv, o[db][3] * inv));
    *(ushort4*)(ob + ((size_t)(b * T_ + tg) * H_ + h) * DH + dh) = st.s4;
  }
}

extern "C" void kernel_launch(void* const* d_in, const int* in_sizes, int n_in,
                              void* d_out, int out_size, void* d_ws, size_t ws_size,
                              hipStream_t stream) {
  const float* x  = (const float*)d_in[0];
  const float* k  = (const float*)d_in[1];
  const float* v  = (const float*)d_in[2];
  const float* wq = (const float*)d_in[3];
  const float* bq = (const float*)d_in[4];
  const float* wo = (const float*)d_in[5];
  const float* bo = (const float*)d_in[6];
  float* out = (float*)d_out;

  char* ws = (char*)d_ws;
  unsigned short* xb  = (unsigned short*)(ws + 0);
  unsigned short* wqb = (unsigned short*)(ws + 16777216);
  unsigned short* wob = (unsigned short*)(ws + 18874368);
  unsigned short* kbp = (unsigned short*)(ws + 20971520);
  unsigned short* vtp = (unsigned short*)(ws + 46137344);
  unsigned short* qsp = (unsigned short*)(ws + 71303168);
  unsigned short* obp = (unsigned short*)(ws + 88080384);

  {
    int blocks = (N1C + 2 * N2C) / 256;
    cast3_kernel<<<blocks, 256, 0, stream>>>(x, wq, wo, xb, wqb, wob);
  }
  {
    int groups = B_ * H_ * SP * 16;
    pack_k_kernel<<<groups / 256, 256, 0, stream>>>(k, kbp);
    pack_vt_kernel<<<dim3(SP / 64, B_ * H_), 256, 0, stream>>>(v, vtp);
  }
  gemm_bt<<<dim3(D_ / 128, B_ * T_ / 128), 256, 0, stream>>>(xb, wqb, bq, qsp, 0);
  attn_kernel<<<dim3(T_ / 128, B_ * H_), 512, 0, stream>>>(qsp, kbp, vtp, obp);
  gemm_bt<<<dim3(D_ / 128, B_ * T_ / 128), 256, 0, stream>>>(obp, wob, bo, out, 1);
}